// Round 8
// baseline (139.677 us; speedup 1.0000x reference)
//
#include <hip/hip_runtime.h>

typedef unsigned short u16;
typedef __bf16 bf16x8 __attribute__((ext_vector_type(8)));
typedef float f32x4 __attribute__((ext_vector_type(4)));

#define AS1 __attribute__((address_space(1)))
#define AS3 __attribute__((address_space(3)))

// B=16, C=512, N=H*W=1024, groups=32 (16 ch/group)

__device__ __forceinline__ u16 f2bf(float f) {
  union { float f; unsigned u; } v; v.f = f;
  return (u16)((v.u + 0x7fffu + ((v.u >> 16) & 1u)) >> 16);
}

__device__ __forceinline__ f32x4 mfma16(bf16x8 a, bf16x8 b, f32x4 c) {
  return __builtin_amdgcn_mfma_f32_16x16x32_bf16(a, b, c, 0, 0, 0);
}

// ---- stage a 128x32 u16 K-tile via global_load_lds (linear LDS dest, XOR seg-swizzle
// applied on per-lane global source; reader applies same XOR).
__device__ __forceinline__ void stage_tile(const u16* __restrict__ src, size_t ld,
                                           u16* lds, int wv, int lane) {
#pragma unroll
  for (int h2 = 0; h2 < 2; h2++) {
    int rbase = wv * 32 + h2 * 16;
    int row = rbase + (lane >> 2);
    int segd = (lane & 3) ^ ((row >> 1) & 3);
    __builtin_amdgcn_global_load_lds(
        (const AS1 void*)(src + (size_t)row * ld + segd * 8),
        (AS3 void*)(lds + rbase * 32), 16, 0, 0);
  }
}

__device__ __forceinline__ bf16x8 ldsfrag(const u16* lds, int row, int rowq) {
  int q = rowq ^ ((row >> 1) & 3);
  return *(const bf16x8*)(lds + row * 32 + q * 8);
}

// ---- 128x128 double-buffered GEMM core, BK=32, counted vmcnt (never drains in-loop).
// 4 waves (2x2), per-wave 64x64 output. Core LDS use = 4 x 4096 u16 = 32 KB.
template<int NT>
__device__ __forceinline__ void gemm_core2(const u16* __restrict__ A, int lda,
                                           const u16* __restrict__ B, int ldb,
                                           u16* lds, f32x4 (&acc)[4][4],
                                           int wave, int lane) {
  u16* sA0 = lds;        u16* sA1 = lds + 4096;
  u16* sB0 = lds + 8192; u16* sB1 = lds + 12288;
  int wm = wave >> 1, wn = wave & 1;
  int col = lane & 15, rq = lane >> 4;
#pragma unroll
  for (int m = 0; m < 4; m++)
#pragma unroll
    for (int n = 0; n < 4; n++) acc[m][n] = (f32x4){0.f, 0.f, 0.f, 0.f};

  stage_tile(A, lda, sA0, wave, lane);
  stage_tile(B, ldb, sB0, wave, lane);
  stage_tile(A + 32, lda, sA1, wave, lane);
  stage_tile(B + 32, ldb, sB1, wave, lane);

  for (int t = 0; t < NT; t++) {
    u16* cA = (t & 1) ? sA1 : sA0;
    u16* cB = (t & 1) ? sB1 : sB0;
    if (t < NT - 1) {
      asm volatile("s_waitcnt vmcnt(4)" ::: "memory");
    } else {
      asm volatile("s_waitcnt vmcnt(0)" ::: "memory");
    }
    __builtin_amdgcn_sched_barrier(0);
    __builtin_amdgcn_s_barrier();
    __builtin_amdgcn_sched_barrier(0);
    bf16x8 af[4], bfr[4];
#pragma unroll
    for (int n = 0; n < 4; n++) bfr[n] = ldsfrag(cB, wn * 64 + n * 16 + col, rq);
#pragma unroll
    for (int m = 0; m < 4; m++) af[m] = ldsfrag(cA, wm * 64 + m * 16 + col, rq);
#pragma unroll
    for (int m = 0; m < 4; m++)
#pragma unroll
      for (int n = 0; n < 4; n++) acc[m][n] = mfma16(af[m], bfr[n], acc[m][n]);
    __builtin_amdgcn_sched_barrier(0);
    __builtin_amdgcn_s_barrier();
    if (t + 2 < NT) {
      stage_tile(A + (size_t)(t + 2) * 32, lda, cA, wave, lane);
      stage_tile(B + (size_t)(t + 2) * 32, ldb, cB, wave, lane);
    }
  }
}

// ---- coalesced epilogue flush: 128 rows x 128 u16 staged in LDS (row stride 132,
// pad -> <=2-way banks) -> 256B-contiguous row chunks; 16 consecutive lanes cover
// 256B of one row => full-line dense stores.
__device__ __forceinline__ void epi_flush(const u16* lds, u16* gdst, size_t stride, int t) {
#pragma unroll
  for (int pass = 0; pass < 8; pass++) {
    int row = pass * 16 + (t >> 4);
    int ch = (t & 15) * 8;
    uint4 w = *(const uint4*)(lds + row * 132 + ch);
    *(uint4*)(gdst + (size_t)row * stride + ch) = w;
  }
}

// ---------------- fused GroupNorm: stats + normalize + transpose, x read once
__global__ __launch_bounds__(256) void gn_fused(const float* __restrict__ x,
                                                const float* __restrict__ gw,
                                                const float* __restrict__ gb,
                                                u16* __restrict__ h) {
  __shared__ float buf[16 * 1032];
  __shared__ float ls[4], lss[4];
  int bg = blockIdx.x;              // b*32 + g
  int b = bg >> 5, g = bg & 31;
  const float4* p = (const float4*)(x + (size_t)bg * 16384);
  float s = 0.f, ss = 0.f;
  for (int i = threadIdx.x; i < 4096; i += 256) {
    float4 v = p[i];
    int c = i >> 8, n = (i & 255) * 4;
    *(float4*)&buf[c * 1032 + n] = v;
    s  += v.x + v.y + v.z + v.w;
    ss += v.x*v.x + v.y*v.y + v.z*v.z + v.w*v.w;
  }
  for (int d = 32; d; d >>= 1) { s += __shfl_down(s, d); ss += __shfl_down(ss, d); }
  int wv = threadIdx.x >> 6;
  if ((threadIdx.x & 63) == 0) { ls[wv] = s; lss[wv] = ss; }
  __syncthreads();
  float m = (ls[0] + ls[1] + ls[2] + ls[3]) * (1.f / 16384.f);
  float var = (lss[0] + lss[1] + lss[2] + lss[3]) * (1.f / 16384.f) - m * m;
  float r = rsqrtf(var + 1e-6f);
  int c0 = g * 16;
  float w[16], bb[16];
#pragma unroll
  for (int c = 0; c < 16; c++) {
    w[c] = gw[c0 + c] * r;
    bb[c] = gb[c0 + c] - m * w[c];
  }
  for (int n = threadIdx.x; n < 1024; n += 256) {
    u16 o[16];
#pragma unroll
    for (int c = 0; c < 16; c++) o[c] = f2bf(buf[c * 1032 + n] * w[c] + bb[c]);
    u16* dst = h + (((size_t)((b << 10) | n)) << 9) + c0;
    *(uint4*)dst = *(uint4*)o;
    *(uint4*)(dst + 8) = *(uint4*)(o + 8);
  }
}

// ---------------- float -> bf16 cast of both weight matrices, one launch
__global__ __launch_bounds__(256) void cast_w(const float* __restrict__ qkv_w,
                                              const float* __restrict__ proj_w,
                                              u16* __restrict__ wq,
                                              u16* __restrict__ wp) {
  int bid = blockIdx.x;
  const float* src = (bid < 768) ? qkv_w : proj_w;
  u16* dst = (bid < 768) ? wq : wp;
  int base = (bid < 768) ? bid * 1024 : (bid - 768) * 1024;
  int i = base + threadIdx.x * 4;
  float4 v = *(const float4*)(src + i);
  dst[i] = f2bf(v.x); dst[i+1] = f2bf(v.y); dst[i+2] = f2bf(v.z); dst[i+3] = f2bf(v.w);
}

// ---------------- QKV GEMM: A=wq[1536][512], B=h[16384][512]
// q_nc[bn][512], k_nc[bn][512], v[c][16384] -- all via LDS-restaged coalesced stores
__global__ __launch_bounds__(256, 4) void gemm_qkv(const u16* __restrict__ A,
                                                   const u16* __restrict__ Bn,
                                                   const float* __restrict__ bias,
                                                   u16* __restrict__ q_nc,
                                                   u16* __restrict__ k_nc,
                                                   u16* __restrict__ v) {
  __shared__ u16 lds[16896];          // core uses [0,16384); epilogue restage 128x132
  int bid = blockIdx.x;               // 1536: 12 mb x 128 nb, XCD n-chunked
  int xcd = bid & 7, r = bid >> 3;    // r 0..191
  int mb = r % 12, nb = xcd * 16 + r / 12;
  int m0 = mb * 128, n0 = nb * 128;
  int t = threadIdx.x, wave = t >> 6, lane = t & 63;
  int wm = wave >> 1, wn = wave & 1;
  int col = lane & 15, rq = lane >> 4;
  f32x4 acc[4][4];
  gemm_core2<16>(A + (size_t)m0 * 512, 512, Bn + (size_t)n0 * 512, 512,
                 lds, acc, wave, lane);
  __syncthreads();
  if (mb < 8) {
    // stage as [bn_local][ch_local]
#pragma unroll
    for (int i = 0; i < 4; i++)
#pragma unroll
      for (int j = 0; j < 4; j++) {
        int o = m0 + wm * 64 + i * 16 + rq * 4;
        u16 tmp[4];
#pragma unroll
        for (int rr = 0; rr < 4; rr++) tmp[rr] = f2bf(acc[i][j][rr] + bias[o + rr]);
        int bnl = wn * 64 + j * 16 + col;
        int chl = wm * 64 + i * 16 + rq * 4;
        *(uint2*)(lds + bnl * 132 + chl) = *(uint2*)tmp;
      }
    __syncthreads();
    u16* dst = ((mb < 4) ? q_nc : k_nc) + (size_t)n0 * 512 + (m0 & 511);
    epi_flush(lds, dst, 512, t);
  } else {
    // stage as [ch_local][bn_local]
#pragma unroll
    for (int i = 0; i < 4; i++)
#pragma unroll
      for (int j = 0; j < 4; j++)
#pragma unroll
        for (int rr = 0; rr < 4; rr++) {
          int o = m0 + wm * 64 + i * 16 + rq * 4 + rr;
          int chl = wm * 64 + i * 16 + rq * 4 + rr;
          int bnl = wn * 64 + j * 16 + col;
          lds[chl * 132 + bnl] = f2bf(acc[i][j][rr] + bias[o]);
        }
    __syncthreads();
    u16* dst = v + (size_t)(m0 - 1024) * 16384 + n0;
    epi_flush(lds, dst, 16384, t);
  }
}

// ---------------- S GEMM per b: E = exp(scale*q.k^T) bf16 + per-tile row partial sums
__global__ __launch_bounds__(256, 4) void gemm_s(const u16* __restrict__ q_nc,
                                                 const u16* __restrict__ k_nc,
                                                 u16* __restrict__ E,
                                                 float* __restrict__ part) {
  __shared__ u16 lds[16896];
  int bid = blockIdx.x;               // 1024: 2 b per XCD, 64 tiles per b
  int xcd = bid & 7, r = bid >> 3;    // 0..127
  int b = xcd * 2 + (r & 1);
  int tile = r >> 1;                  // 0..63
  int m0 = (tile >> 3) * 128, n0 = (tile & 7) * 128;
  int t = threadIdx.x, wave = t >> 6, lane = t & 63;
  int wm = wave >> 1, wn = wave & 1;
  int col = lane & 15, rq = lane >> 4;
  f32x4 acc[4][4];
  gemm_core2<16>(q_nc + ((size_t)(b * 1024 + m0)) * 512, 512,
                 k_nc + ((size_t)(b * 1024 + n0)) * 512, 512,
                 lds, acc, wave, lane);
  float* pb = part + ((size_t)b << 14);
  int idx = (n0 >> 6) + wn;           // 0..15 column-chunk id
  const float scale = 0.04419417382415922f;  // 512^-0.5
  __syncthreads();
#pragma unroll
  for (int i = 0; i < 4; i++)
#pragma unroll
    for (int rr = 0; rr < 4; rr++) {
      float e[4], rs = 0.f;
#pragma unroll
      for (int j = 0; j < 4; j++) { e[j] = __expf(acc[i][j][rr] * scale); rs += e[j]; }
      rs += __shfl_xor(rs, 1); rs += __shfl_xor(rs, 2);
      rs += __shfl_xor(rs, 4); rs += __shfl_xor(rs, 8);
      int iil = wm * 64 + i * 16 + rq * 4 + rr;
      if (col == 0) pb[(m0 + iil) * 16 + idx] = rs;
#pragma unroll
      for (int j = 0; j < 4; j++)
        lds[iil * 132 + wn * 64 + j * 16 + col] = f2bf(e[j]);
    }
  __syncthreads();
  epi_flush(lds, E + ((size_t)b << 20) + (size_t)m0 * 1024 + n0, 1024, t);
}

// ---------------- inv[row] = 1 / sum of 16 partials
__global__ __launch_bounds__(256) void row_inv2(const float* __restrict__ part,
                                                float* __restrict__ inv) {
  int row = blockIdx.x * 256 + threadIdx.x;
  const float4* p = (const float4*)(part + (size_t)row * 16);
  float4 a = p[0], b = p[1], c = p[2], d = p[3];
  float s = a.x+a.y+a.z+a.w + b.x+b.y+b.z+b.w + c.x+c.y+c.z+c.w + d.x+d.y+d.z+d.w;
  inv[row] = 1.f / s;
}

// ---------------- PV GEMM per b: O[i][c] = inv[i]*sum_j E[i][j]*v[c][j] -> o_nc[bn][c]
__global__ __launch_bounds__(256, 4) void gemm_pv(const u16* __restrict__ E,
                                                  const u16* __restrict__ v,
                                                  const float* __restrict__ inv,
                                                  u16* __restrict__ o_nc) {
  __shared__ u16 lds[16896];
  int bid = blockIdx.x;               // 512: 2 b per XCD, 32 tiles per b
  int xcd = bid & 7, r = bid >> 3;    // 0..63
  int b = xcd * 2 + (r & 1);
  int tile = r >> 1;                  // 0..31
  int m0 = (tile >> 2) * 128, n0 = (tile & 3) * 128;
  int t = threadIdx.x, wave = t >> 6, lane = t & 63;
  int wm = wave >> 1, wn = wave & 1;
  int col = lane & 15, rq = lane >> 4;
  f32x4 acc[4][4];
  gemm_core2<32>(E + ((size_t)b << 20) + (size_t)m0 * 1024, 1024,
                 v + (size_t)n0 * 16384 + ((size_t)b << 10), 16384,
                 lds, acc, wave, lane);
  __syncthreads();
#pragma unroll
  for (int i = 0; i < 4; i++)
#pragma unroll
    for (int rr = 0; rr < 4; rr++) {
      int iil = wm * 64 + i * 16 + rq * 4 + rr;
      float sc = inv[(b << 10) + m0 + iil];
#pragma unroll
      for (int j = 0; j < 4; j++)
        lds[iil * 132 + wn * 64 + j * 16 + col] = f2bf(acc[i][j][rr] * sc);
    }
  __syncthreads();
  epi_flush(lds, o_nc + ((size_t)(b * 1024 + m0)) * 512 + n0, 512, t);
}

// ---------------- proj GEMM + bias + residual -> fp32 out[b][co][n]
// (direct stores: 16 consecutive lanes already write full 64B lines)
__global__ __launch_bounds__(256, 4) void gemm_proj(const u16* __restrict__ A,
                                                    const u16* __restrict__ Bn,
                                                    const float* __restrict__ bias,
                                                    const float* __restrict__ xres,
                                                    float* __restrict__ outp) {
  __shared__ u16 lds[16384];
  int bid = blockIdx.x;               // 512: 4 mb x 128 nb, XCD n-chunked
  int xcd = bid & 7, r = bid >> 3;    // 0..63
  int mb = r & 3, nb = xcd * 16 + (r >> 2);
  int m0 = mb * 128, n0 = nb * 128;
  int t = threadIdx.x, wave = t >> 6, lane = t & 63;
  int wm = wave >> 1, wn = wave & 1;
  int col = lane & 15, rq = lane >> 4;
  f32x4 acc[4][4];
  gemm_core2<16>(A + (size_t)m0 * 512, 512, Bn + (size_t)n0 * 512, 512,
                 lds, acc, wave, lane);
#pragma unroll
  for (int i = 0; i < 4; i++)
#pragma unroll
    for (int j = 0; j < 4; j++)
#pragma unroll
      for (int rr = 0; rr < 4; rr++) {
        int co = m0 + wm * 64 + i * 16 + rq * 4 + rr;
        int bn = n0 + wn * 64 + j * 16 + col;
        int bb = bn >> 10, n = bn & 1023;
        size_t oi = (((size_t)(bb * 512 + co)) << 10) + n;
        outp[oi] = acc[i][j][rr] + bias[co] + xres[oi];
      }
}

extern "C" void kernel_launch(void* const* d_in, const int* in_sizes, int n_in,
                              void* d_out, int out_size, void* d_ws, size_t ws_size,
                              hipStream_t stream) {
  const float* x      = (const float*)d_in[0];
  const float* norm_w = (const float*)d_in[1];
  const float* norm_b = (const float*)d_in[2];
  const float* qkv_w  = (const float*)d_in[3];
  const float* qkv_b  = (const float*)d_in[4];
  const float* proj_w = (const float*)d_in[5];
  const float* proj_b = (const float*)d_in[6];
  float* out = (float*)d_out;

  char* ws = (char*)d_ws;
  size_t off = 0;
  auto alloc = [&](size_t bytes) {
    void* p = ws + off;
    off += (bytes + 255) & ~(size_t)255;
    return p;
  };
  float* part = (float*)alloc((size_t)16384 * 16 * 4);
  float* inv  = (float*)alloc(16384 * 4);
  u16* wq   = (u16*)alloc((size_t)1536 * 512 * 2);
  u16* wp   = (u16*)alloc((size_t)512 * 512 * 2);
  u16* h    = (u16*)alloc((size_t)16384 * 512 * 2);   // reused as o_nc
  u16* q_nc = (u16*)alloc((size_t)16384 * 512 * 2);
  u16* k_nc = (u16*)alloc((size_t)16384 * 512 * 2);
  u16* v    = (u16*)alloc((size_t)512 * 16384 * 2);
  u16* E    = (u16*)alloc((size_t)16 * 1024 * 1024 * 2);
  u16* o_nc = h;
  (void)in_sizes; (void)n_in; (void)out_size; (void)ws_size;

  gn_fused<<<512, 256, 0, stream>>>(x, norm_w, norm_b, h);
  cast_w<<<1024, 256, 0, stream>>>(qkv_w, proj_w, wq, wp);
  gemm_qkv<<<1536, 256, 0, stream>>>(wq, h, qkv_b, q_nc, k_nc, v);
  gemm_s<<<1024, 256, 0, stream>>>(q_nc, k_nc, E, part);
  row_inv2<<<64, 256, 0, stream>>>(part, inv);
  gemm_pv<<<512, 256, 0, stream>>>(E, v, inv, o_nc);
  gemm_proj<<<512, 256, 0, stream>>>(wp, o_nc, proj_b, x, out);
}

// Round 9
// 132.320 us; speedup vs baseline: 1.0556x; 1.0556x over previous
//
#include <hip/hip_runtime.h>

typedef unsigned short u16;
typedef __bf16 bf16x8 __attribute__((ext_vector_type(8)));
typedef float f32x4 __attribute__((ext_vector_type(4)));

#define AS1 __attribute__((address_space(1)))
#define AS3 __attribute__((address_space(3)))

// B=16, C=512, N=H*W=1024, groups=32 (16 ch/group)

__device__ __forceinline__ u16 f2bf(float f) {
  union { float f; unsigned u; } v; v.f = f;
  return (u16)((v.u + 0x7fffu + ((v.u >> 16) & 1u)) >> 16);
}

__device__ __forceinline__ f32x4 mfma16(bf16x8 a, bf16x8 b, f32x4 c) {
  return __builtin_amdgcn_mfma_f32_16x16x32_bf16(a, b, c, 0, 0, 0);
}

// ================= 128x128 2-buffer core =================
__device__ __forceinline__ void stage_tile(const u16* __restrict__ src, size_t ld,
                                           u16* lds, int wv, int lane) {
#pragma unroll
  for (int h2 = 0; h2 < 2; h2++) {
    int rbase = wv * 32 + h2 * 16;
    int row = rbase + (lane >> 2);
    int segd = (lane & 3) ^ ((row >> 1) & 3);
    __builtin_amdgcn_global_load_lds(
        (const AS1 void*)(src + (size_t)row * ld + segd * 8),
        (AS3 void*)(lds + rbase * 32), 16, 0, 0);
  }
}

__device__ __forceinline__ bf16x8 ldsfrag(const u16* lds, int row, int rowq) {
  int q = rowq ^ ((row >> 1) & 3);
  return *(const bf16x8*)(lds + row * 32 + q * 8);
}

template<int NT>
__device__ __forceinline__ void gemm_core2(const u16* __restrict__ A, int lda,
                                           const u16* __restrict__ B, int ldb,
                                           u16* lds, f32x4 (&acc)[4][4],
                                           int wave, int lane) {
  u16* sA0 = lds;        u16* sA1 = lds + 4096;
  u16* sB0 = lds + 8192; u16* sB1 = lds + 12288;
  int wm = wave >> 1, wn = wave & 1;
  int col = lane & 15, rq = lane >> 4;
#pragma unroll
  for (int m = 0; m < 4; m++)
#pragma unroll
    for (int n = 0; n < 4; n++) acc[m][n] = (f32x4){0.f, 0.f, 0.f, 0.f};

  stage_tile(A, lda, sA0, wave, lane);
  stage_tile(B, ldb, sB0, wave, lane);
  stage_tile(A + 32, lda, sA1, wave, lane);
  stage_tile(B + 32, ldb, sB1, wave, lane);

  for (int t = 0; t < NT; t++) {
    u16* cA = (t & 1) ? sA1 : sA0;
    u16* cB = (t & 1) ? sB1 : sB0;
    if (t < NT - 1) {
      asm volatile("s_waitcnt vmcnt(4)" ::: "memory");
    } else {
      asm volatile("s_waitcnt vmcnt(0)" ::: "memory");
    }
    __builtin_amdgcn_sched_barrier(0);
    __builtin_amdgcn_s_barrier();
    __builtin_amdgcn_sched_barrier(0);
    bf16x8 af[4], bfr[4];
#pragma unroll
    for (int n = 0; n < 4; n++) bfr[n] = ldsfrag(cB, wn * 64 + n * 16 + col, rq);
#pragma unroll
    for (int m = 0; m < 4; m++) af[m] = ldsfrag(cA, wm * 64 + m * 16 + col, rq);
#pragma unroll
    for (int m = 0; m < 4; m++)
#pragma unroll
      for (int n = 0; n < 4; n++) acc[m][n] = mfma16(af[m], bfr[n], acc[m][n]);
    __builtin_amdgcn_sched_barrier(0);
    __builtin_amdgcn_s_barrier();
    if (t + 2 < NT) {
      stage_tile(A + (size_t)(t + 2) * 32, lda, cA, wave, lane);
      stage_tile(B + (size_t)(t + 2) * 32, ldb, cB, wave, lane);
    }
  }
}

// ---- coalesced epilogue flush (128x128 tile staged at row stride 132)
__device__ __forceinline__ void epi_flush(const u16* lds, u16* gdst, size_t stride, int t) {
#pragma unroll
  for (int pass = 0; pass < 8; pass++) {
    int row = pass * 16 + (t >> 4);
    int ch = (t & 15) * 8;
    uint4 w = *(const uint4*)(lds + row * 132 + ch);
    *(uint4*)(gdst + (size_t)row * stride + ch) = w;
  }
}

// ================= 256x256 8-phase core (s) =================
__device__ __forceinline__ void stage_half(const u16* __restrict__ src, size_t ld,
                                           u16* ldsbase, int wave, int lane) {
#pragma unroll
  for (int r = 0; r < 2; r++) {
    int rb = (r * 8 + wave) * 8;
    int row = rb + (lane >> 3);
    int seg = (lane & 7) ^ (row & 7);
    __builtin_amdgcn_global_load_lds(
        (const AS1 void*)(src + (size_t)row * ld + seg * 8),
        (AS3 void*)(ldsbase + rb * 64), 16, 0, 0);
  }
}

template<int P>
__device__ __forceinline__ void phase_read(const u16* cA, const u16* cB,
                                           bf16x8 (&af)[2][2], bf16x8 (&bfr)[4][2],
                                           int wm, int wn, int col, int rq) {
  if constexpr (P == 0) {
#pragma unroll
    for (int nf = 0; nf < 4; nf++)
#pragma unroll
      for (int kk = 0; kk < 2; kk++) {
        int row = wn * 64 + nf * 16 + col;
        bfr[nf][kk] = *(const bf16x8*)(cB + row * 64 + (((kk << 2) + rq) ^ (row & 7)) * 8);
      }
  }
#pragma unroll
  for (int i = 0; i < 2; i++)
#pragma unroll
    for (int kk = 0; kk < 2; kk++) {
      int row = wm * 128 + (P * 2 + i) * 16 + col;
      af[i][kk] = *(const bf16x8*)(cA + row * 64 + (((kk << 2) + rq) ^ (row & 7)) * 8);
    }
}

template<int P>
__device__ __forceinline__ void phase_fma(const bf16x8 (&af)[2][2],
                                          const bf16x8 (&bfr)[4][2],
                                          f32x4 (&acc)[8][4]) {
#pragma unroll
  for (int i = 0; i < 2; i++)
#pragma unroll
    for (int kk = 0; kk < 2; kk++)
#pragma unroll
      for (int nf = 0; nf < 4; nf++)
        acc[P * 2 + i][nf] = mfma16(af[i][kk], bfr[nf][kk], acc[P * 2 + i][nf]);
}

#define RUN_PHASE(P, STAGE_CODE, WAIT_CODE)                                  \
  {                                                                          \
    bf16x8 af[2][2];                                                         \
    phase_read<P>(cA, cB, af, bfr, wm, wn, col, rq);                         \
    STAGE_CODE;                                                              \
    WAIT_CODE;                                                               \
    __builtin_amdgcn_sched_barrier(0);                                       \
    __builtin_amdgcn_s_barrier();                                            \
    __builtin_amdgcn_sched_barrier(0);                                       \
    __builtin_amdgcn_s_setprio(1);                                           \
    phase_fma<P>(af, bfr, acc);                                              \
    __builtin_amdgcn_s_setprio(0);                                           \
    __builtin_amdgcn_sched_barrier(0);                                       \
    __builtin_amdgcn_s_barrier();                                            \
    __builtin_amdgcn_sched_barrier(0);                                       \
  }

template<int NT>
__device__ __forceinline__ void gemm8_core(const u16* __restrict__ A, int lda,
                                           const u16* __restrict__ B, int ldb,
                                           u16* lds, f32x4 (&acc)[8][4],
                                           int wave, int lane) {
  u16* Abuf[2] = {lds, lds + 16384};
  u16* Bbuf[2] = {lds + 32768, lds + 49152};
  int wm = wave >> 2, wn = wave & 3;
  int col = lane & 15, rq = lane >> 4;
#pragma unroll
  for (int m = 0; m < 8; m++)
#pragma unroll
    for (int n = 0; n < 4; n++) acc[m][n] = (f32x4){0.f, 0.f, 0.f, 0.f};

  stage_half(A, lda, Abuf[0], wave, lane);
  stage_half(A + 128 * (size_t)lda, lda, Abuf[0] + 8192, wave, lane);
  stage_half(B, ldb, Bbuf[0], wave, lane);
  stage_half(B + 128 * (size_t)ldb, ldb, Bbuf[0] + 8192, wave, lane);
  stage_half(B + 64, ldb, Bbuf[1], wave, lane);
  stage_half(B + 64 + 128 * (size_t)ldb, ldb, Bbuf[1] + 8192, wave, lane);
  asm volatile("s_waitcnt vmcnt(4)" ::: "memory");
  __builtin_amdgcn_sched_barrier(0);
  __builtin_amdgcn_s_barrier();
  __builtin_amdgcn_sched_barrier(0);

  for (int kt = 0; kt < NT; kt++) {
    const u16* cA = Abuf[kt & 1];
    const u16* cB = Bbuf[kt & 1];
    u16* nA = Abuf[(kt + 1) & 1];
    u16* nB = Bbuf[kt & 1];
    const u16* Asrc = A + (size_t)(kt + 1) * 64;
    const u16* Bsrc = B + (size_t)(kt + 2) * 64;
    bool pa = (kt + 1 < NT), pb = (kt + 2 < NT);
    bf16x8 bfr[4][2];
    RUN_PHASE(0, if (pa) stage_half(Asrc, lda, nA, wave, lane), );
    RUN_PHASE(1, if (pa) stage_half(Asrc + 128 * (size_t)lda, lda, nA + 8192, wave, lane), );
    RUN_PHASE(2, if (pb) stage_half(Bsrc, ldb, nB, wave, lane), );
    RUN_PHASE(3, if (pb) stage_half(Bsrc + 128 * (size_t)ldb, ldb, nB + 8192, wave, lane),
              if (pb) { asm volatile("s_waitcnt vmcnt(4)" ::: "memory"); }
              else    { asm volatile("s_waitcnt vmcnt(0)" ::: "memory"); });
  }
}

// ---------------- fused GroupNorm + weight casts
__global__ __launch_bounds__(256) void gn_fused(const float* __restrict__ x,
                                                const float* __restrict__ gw,
                                                const float* __restrict__ gb,
                                                const float* __restrict__ qkv_w,
                                                const float* __restrict__ proj_w,
                                                u16* __restrict__ h,
                                                u16* __restrict__ wq,
                                                u16* __restrict__ wp) {
  __shared__ float buf[16 * 1032];
  __shared__ float ls[4], lss[4];
  int bg = blockIdx.x;              // b*32 + g
  int b = bg >> 5, g = bg & 31;
  const float4* p = (const float4*)(x + (size_t)bg * 16384);
  float s = 0.f, ss = 0.f;
  for (int i = threadIdx.x; i < 4096; i += 256) {
    float4 v = p[i];
    int c = i >> 8, n = (i & 255) * 4;
    *(float4*)&buf[c * 1032 + n] = v;
    s  += v.x + v.y + v.z + v.w;
    ss += v.x*v.x + v.y*v.y + v.z*v.z + v.w*v.w;
  }
  // weight cast slice for this block: 1536 qkv_w floats + 512 proj_w floats
  {
    int qb = bg * 384;              // float4 units
    for (int u = threadIdx.x; u < 384; u += 256) {
      float4 v = *(const float4*)(qkv_w + (size_t)(qb + u) * 4);
      int o = (qb + u) * 4;
      wq[o] = f2bf(v.x); wq[o+1] = f2bf(v.y); wq[o+2] = f2bf(v.z); wq[o+3] = f2bf(v.w);
    }
    int pb = bg * 128;
    if (threadIdx.x < 128) {
      float4 v = *(const float4*)(proj_w + (size_t)(pb + threadIdx.x) * 4);
      int o = (pb + threadIdx.x) * 4;
      wp[o] = f2bf(v.x); wp[o+1] = f2bf(v.y); wp[o+2] = f2bf(v.z); wp[o+3] = f2bf(v.w);
    }
  }
  for (int d = 32; d; d >>= 1) { s += __shfl_down(s, d); ss += __shfl_down(ss, d); }
  int wv = threadIdx.x >> 6;
  if ((threadIdx.x & 63) == 0) { ls[wv] = s; lss[wv] = ss; }
  __syncthreads();
  float m = (ls[0] + ls[1] + ls[2] + ls[3]) * (1.f / 16384.f);
  float var = (lss[0] + lss[1] + lss[2] + lss[3]) * (1.f / 16384.f) - m * m;
  float r = rsqrtf(var + 1e-6f);
  int c0 = g * 16;
  float w[16], bb[16];
#pragma unroll
  for (int c = 0; c < 16; c++) {
    w[c] = gw[c0 + c] * r;
    bb[c] = gb[c0 + c] - m * w[c];
  }
  for (int n = threadIdx.x; n < 1024; n += 256) {
    u16 o[16];
#pragma unroll
    for (int c = 0; c < 16; c++) o[c] = f2bf(buf[c * 1032 + n] * w[c] + bb[c]);
    u16* dst = h + (((size_t)((b << 10) | n)) << 9) + c0;
    *(uint4*)dst = *(uint4*)o;
    *(uint4*)(dst + 8) = *(uint4*)(o + 8);
  }
}

// ---------------- QKV GEMM (128^2 core, coalesced epilogues)
__global__ __launch_bounds__(256, 4) void gemm_qkv(const u16* __restrict__ A,
                                                   const u16* __restrict__ Bn,
                                                   const float* __restrict__ bias,
                                                   u16* __restrict__ q_nc,
                                                   u16* __restrict__ k_nc,
                                                   u16* __restrict__ v) {
  __shared__ u16 lds[16896];
  int bid = blockIdx.x;               // 1536: 12 mb x 128 nb, XCD n-chunked
  int xcd = bid & 7, r = bid >> 3;
  int mb = r % 12, nb = xcd * 16 + r / 12;
  int m0 = mb * 128, n0 = nb * 128;
  int t = threadIdx.x, wave = t >> 6, lane = t & 63;
  int wm = wave >> 1, wn = wave & 1;
  int col = lane & 15, rq = lane >> 4;
  f32x4 acc[4][4];
  gemm_core2<16>(A + (size_t)m0 * 512, 512, Bn + (size_t)n0 * 512, 512,
                 lds, acc, wave, lane);
  __syncthreads();
  if (mb < 8) {
#pragma unroll
    for (int i = 0; i < 4; i++)
#pragma unroll
      for (int j = 0; j < 4; j++) {
        int o = m0 + wm * 64 + i * 16 + rq * 4;
        u16 tmp[4];
#pragma unroll
        for (int rr = 0; rr < 4; rr++) tmp[rr] = f2bf(acc[i][j][rr] + bias[o + rr]);
        int bnl = wn * 64 + j * 16 + col;
        int chl = wm * 64 + i * 16 + rq * 4;
        *(uint2*)(lds + bnl * 132 + chl) = *(uint2*)tmp;
      }
    __syncthreads();
    u16* dst = ((mb < 4) ? q_nc : k_nc) + (size_t)n0 * 512 + (m0 & 511);
    epi_flush(lds, dst, 512, t);
  } else {
#pragma unroll
    for (int i = 0; i < 4; i++)
#pragma unroll
      for (int j = 0; j < 4; j++)
#pragma unroll
        for (int rr = 0; rr < 4; rr++) {
          int o = m0 + wm * 64 + i * 16 + rq * 4 + rr;
          int chl = wm * 64 + i * 16 + rq * 4 + rr;
          int bnl = wn * 64 + j * 16 + col;
          lds[chl * 132 + bnl] = f2bf(acc[i][j][rr] + bias[o]);
        }
    __syncthreads();
    u16* dst = v + (size_t)(m0 - 1024) * 16384 + n0;
    epi_flush(lds, dst, 16384, t);
  }
}

// ---------------- S GEMM (8-phase 256^2) per b: E = exp(scale*q.k^T) + row partials
// Coalesced E stores via core-LDS restage (256x256, involutive 16B-block XOR swizzle).
__global__ __launch_bounds__(512, 1) void gemm8_s(const u16* __restrict__ q_nc,
                                                  const u16* __restrict__ k_nc,
                                                  u16* __restrict__ E,
                                                  float* __restrict__ part) {
  __shared__ u16 lds[65536];
  int bid = blockIdx.x;               // 256: 2 b per XCD, 16 tiles per b
  int xcd = bid & 7, r = bid >> 3;
  int b = xcd * 2 + (r & 1);
  int tile = r >> 1;                  // 0..15
  int m0 = (tile >> 2) * 256, n0 = (tile & 3) * 256;
  int t = threadIdx.x, wave = t >> 6, lane = t & 63;
  int wm = wave >> 2, wn = wave & 3;
  int col = lane & 15, rq = lane >> 4;
  f32x4 acc[8][4];
  gemm8_core<8>(q_nc + ((size_t)(b * 1024 + m0)) * 512, 512,
                k_nc + ((size_t)(b * 1024 + n0)) * 512, 512,
                lds, acc, wave, lane);
  float* pb = part + ((size_t)b << 14);
  int idx = (n0 >> 6) + wn;           // 0..15 column-chunk id
  const float scale = 0.04419417382415922f;  // 512^-0.5
  __syncthreads();
#pragma unroll
  for (int mf = 0; mf < 8; mf++)
#pragma unroll
    for (int rr = 0; rr < 4; rr++) {
      float e[4], rs = 0.f;
#pragma unroll
      for (int nf = 0; nf < 4; nf++) { e[nf] = __expf(acc[mf][nf][rr] * scale); rs += e[nf]; }
      rs += __shfl_xor(rs, 1); rs += __shfl_xor(rs, 2);
      rs += __shfl_xor(rs, 4); rs += __shfl_xor(rs, 8);
      int il = wm * 128 + mf * 16 + rq * 4 + rr;
      if (col == 0) pb[(m0 + il) * 16 + idx] = rs;
#pragma unroll
      for (int nf = 0; nf < 4; nf++) {
        int j = wn * 64 + nf * 16 + col;
        int jb = (j >> 3) ^ (il & 7);
        lds[il * 256 + (jb << 3) + (j & 7)] = f2bf(e[nf]);
      }
    }
  __syncthreads();
  // flush: 512 threads, 32 lanes cover one 256-u16 row; 16 rows/pass, 16 passes
  u16* Eb = E + ((size_t)b << 20) + (size_t)m0 * 1024 + n0;
#pragma unroll
  for (int pass = 0; pass < 16; pass++) {
    int row = pass * 16 + (t >> 5);
    int jbl = t & 31;
    uint4 w = *(const uint4*)(lds + row * 256 + (jbl << 3));
    int jb = jbl ^ (row & 7);
    *(uint4*)(Eb + (size_t)row * 1024 + (jb << 3)) = w;
  }
}

// ---------------- PV GEMM per b (+inline row-inv): O[i][c] = inv[i]*sum_j E[i][j]*v[c][j]
__global__ __launch_bounds__(256, 4) void gemm_pv(const u16* __restrict__ E,
                                                  const u16* __restrict__ v,
                                                  const float* __restrict__ part,
                                                  u16* __restrict__ o_nc) {
  __shared__ u16 lds[16896];
  __shared__ float invs[128];
  int bid = blockIdx.x;               // 512: 2 b per XCD, 32 tiles per b
  int xcd = bid & 7, r = bid >> 3;
  int b = xcd * 2 + (r & 1);
  int tile = r >> 1;                  // 0..31
  int m0 = (tile >> 2) * 128, n0 = (tile & 3) * 128;
  int t = threadIdx.x, wave = t >> 6, lane = t & 63;
  int wm = wave >> 1, wn = wave & 1;
  int col = lane & 15, rq = lane >> 4;
  f32x4 acc[4][4];
  gemm_core2<32>(E + ((size_t)b << 20) + (size_t)m0 * 1024, 1024,
                 v + (size_t)n0 * 16384 + ((size_t)b << 10), 16384,
                 lds, acc, wave, lane);
  if (t < 128) {
    const float4* p = (const float4*)(part + ((size_t)((b << 10) + m0 + t)) * 16);
    float4 a = p[0], bq = p[1], c = p[2], d = p[3];
    float s = a.x+a.y+a.z+a.w + bq.x+bq.y+bq.z+bq.w + c.x+c.y+c.z+c.w + d.x+d.y+d.z+d.w;
    invs[t] = 1.f / s;
  }
  __syncthreads();
#pragma unroll
  for (int i = 0; i < 4; i++)
#pragma unroll
    for (int rr = 0; rr < 4; rr++) {
      int iil = wm * 64 + i * 16 + rq * 4 + rr;
      float sc = invs[iil];
#pragma unroll
      for (int j = 0; j < 4; j++)
        lds[iil * 132 + wn * 64 + j * 16 + col] = f2bf(acc[i][j][rr] * sc);
    }
  __syncthreads();
  epi_flush(lds, o_nc + ((size_t)(b * 1024 + m0)) * 512 + n0, 512, t);
}

// ---------------- proj GEMM + bias + residual -> fp32 out[b][co][n]
__global__ __launch_bounds__(256, 4) void gemm_proj(const u16* __restrict__ A,
                                                    const u16* __restrict__ Bn,
                                                    const float* __restrict__ bias,
                                                    const float* __restrict__ xres,
                                                    float* __restrict__ outp) {
  __shared__ u16 lds[16384];
  int bid = blockIdx.x;               // 512: 4 mb x 128 nb, XCD n-chunked
  int xcd = bid & 7, r = bid >> 3;
  int mb = r & 3, nb = xcd * 16 + (r >> 2);
  int m0 = mb * 128, n0 = nb * 128;
  int t = threadIdx.x, wave = t >> 6, lane = t & 63;
  int wm = wave >> 1, wn = wave & 1;
  int col = lane & 15, rq = lane >> 4;
  f32x4 acc[4][4];
  gemm_core2<16>(A + (size_t)m0 * 512, 512, Bn + (size_t)n0 * 512, 512,
                 lds, acc, wave, lane);
#pragma unroll
  for (int i = 0; i < 4; i++)
#pragma unroll
    for (int j = 0; j < 4; j++)
#pragma unroll
      for (int rr = 0; rr < 4; rr++) {
        int co = m0 + wm * 64 + i * 16 + rq * 4 + rr;
        int bn = n0 + wn * 64 + j * 16 + col;
        int bb = bn >> 10, n = bn & 1023;
        size_t oi = (((size_t)(bb * 512 + co)) << 10) + n;
        outp[oi] = acc[i][j][rr] + bias[co] + xres[oi];
      }
}

extern "C" void kernel_launch(void* const* d_in, const int* in_sizes, int n_in,
                              void* d_out, int out_size, void* d_ws, size_t ws_size,
                              hipStream_t stream) {
  const float* x      = (const float*)d_in[0];
  const float* norm_w = (const float*)d_in[1];
  const float* norm_b = (const float*)d_in[2];
  const float* qkv_w  = (const float*)d_in[3];
  const float* qkv_b  = (const float*)d_in[4];
  const float* proj_w = (const float*)d_in[5];
  const float* proj_b = (const float*)d_in[6];
  float* out = (float*)d_out;

  char* ws = (char*)d_ws;
  size_t off = 0;
  auto alloc = [&](size_t bytes) {
    void* p = ws + off;
    off += (bytes + 255) & ~(size_t)255;
    return p;
  };
  float* part = (float*)alloc((size_t)16384 * 16 * 4);
  u16* wq   = (u16*)alloc((size_t)1536 * 512 * 2);
  u16* wp   = (u16*)alloc((size_t)512 * 512 * 2);
  u16* h    = (u16*)alloc((size_t)16384 * 512 * 2);   // reused as o_nc
  u16* q_nc = (u16*)alloc((size_t)16384 * 512 * 2);
  u16* k_nc = (u16*)alloc((size_t)16384 * 512 * 2);
  u16* v    = (u16*)alloc((size_t)512 * 16384 * 2);
  u16* E    = (u16*)alloc((size_t)16 * 1024 * 1024 * 2);
  u16* o_nc = h;
  (void)in_sizes; (void)n_in; (void)out_size; (void)ws_size;

  gn_fused<<<512, 256, 0, stream>>>(x, norm_w, norm_b, qkv_w, proj_w, h, wq, wp);
  gemm_qkv<<<1536, 256, 0, stream>>>(wq, h, qkv_b, q_nc, k_nc, v);
  gemm8_s<<<256, 512, 0, stream>>>(q_nc, k_nc, E, part);
  gemm_pv<<<512, 256, 0, stream>>>(E, v, part, o_nc);
  gemm_proj<<<512, 256, 0, stream>>>(wp, o_nc, proj_b, x, out);
}